// Round 14
// baseline (25650.577 us; speedup 1.0000x reference)
//
#include <hip/hip_runtime.h>
#include <cstddef>

#define T_LEN 32768
#define HID   300
#define HP    304   // padded row width for x/h buffers
#define HK    320   // padded K for MFMA (10 chunks of 32)
#define KC    10
#define IN_D  500
#define OUT_D 100
#define OUTP  104
#define DIST  4     // x prefetch distance (steps) = slot count
#define CHUNK 64
#define NCHUNK (T_LEN / CHUNK)
#define NWAVE 12    // 768 threads, 3 waves/SIMD

typedef _Float16 f16x8 __attribute__((ext_vector_type(8)));
typedef float    f32x4 __attribute__((ext_vector_type(4)));

// Static device scratch
__device__ __align__(16) float    g_x  [(size_t)(T_LEN + 8) * HP];    // x0
__device__ __align__(16) float    g_x1 [(size_t)(T_LEN + 8) * HP];    // x1
__device__ __align__(16) _Float16 g_h0h[(size_t)T_LEN * HP + 64];     // h0, f16
__device__ __align__(16) _Float16 g_h1h[(size_t)T_LEN * HP + 64];     // h1, f16
__device__ __align__(16) float    g_wt0[IN_D * HP];
__device__ __align__(16) float    g_wtl[HID * OUTP];
__device__ int g_flag0;   // chunks of h0 published by scan0
__device__ int g_flag1;   // chunks of x1 published by proj1

// ---------------- reset flags (graph replays!) ----------------
__global__ void k_reset() { g_flag0 = 0; g_flag1 = 0; }

// ---------------- transpose + pad: dst[k][j] = (j<J) ? src[j][k] : 0 ----------------
__global__ void k_transpose(const float* __restrict__ src, int J, int K, int JP, int dst_sel)
{
    float* dst = (dst_sel == 0) ? g_wt0 : g_wtl;
    int idx = blockIdx.x * 256 + threadIdx.x;
    if (idx >= K * JP) return;
    int k = idx / JP, j = idx - k * JP;
    dst[idx] = (j < J) ? src[j * K + k] : 0.f;
}

// ---------------- x0 = input @ W_ih0^T + (b_ih0+b_hh0), 32 rows per block ----------------
__global__ __launch_bounds__(320) void k_gemm_in(const float* __restrict__ inp,
                                                 const float* __restrict__ b1,
                                                 const float* __restrict__ b2)
{
    __shared__ float lds[32 * IN_D];
    const int tid = threadIdx.x;
    const int t0  = blockIdx.x * 32;
    {
        const f32x4* src4 = (const f32x4*)(inp + (size_t)t0 * IN_D);
        f32x4* lds4 = (f32x4*)lds;
        const int n4 = (32 * IN_D) >> 2;
        for (int i = tid; i < n4; i += 320) lds4[i] = src4[i];
    }
    __syncthreads();
    const int j = tid;
    if (j >= HP) return;
    float acc[32];
#pragma unroll
    for (int i = 0; i < 32; i++) acc[i] = 0.f;
#pragma unroll 4
    for (int k = 0; k < IN_D; k++) {
        float w = g_wt0[k * HP + j];
#pragma unroll
        for (int i = 0; i < 32; i++) acc[i] += w * lds[i * IN_D + k];  // uniform addr -> broadcast
    }
    const float bias = (j < HID) ? (b1[j] + b2[j]) : 0.f;
#pragma unroll 4
    for (int i = 0; i < 32; i++) g_x[(size_t)(t0 + i) * HP + j] = acc[i] + bias;
}

// ---------------- out = h1(f16) @ WTl + b_lin, 64 rows per block ----------------
__global__ __launch_bounds__(128) void k_gemm_out(const float* __restrict__ blin,
                                                  float* __restrict__ out)
{
    __shared__ float lds[64 * HP];
    const int tid = threadIdx.x;
    const int t0  = blockIdx.x * 64;
    {
        const f16x8* src8 = (const f16x8*)(g_h1h + (size_t)t0 * HP);
        const int n8 = (64 * HP) / 8;
        for (int i = tid; i < n8; i += 128) {
            f16x8 v = src8[i];
            float* d = &lds[i * 8];
#pragma unroll
            for (int e = 0; e < 8; e++) d[e] = (float)v[e];
        }
    }
    __syncthreads();
    const int j = tid;
    if (j >= OUTP) return;
    float acc[64];
#pragma unroll
    for (int i = 0; i < 64; i++) acc[i] = 0.f;
#pragma unroll 2
    for (int k = 0; k < HID; k++) {
        float w = g_wtl[k * OUTP + j];
#pragma unroll
        for (int i = 0; i < 64; i++) acc[i] += w * lds[i * HP + k];
    }
    if (j < OUT_D) {
        float b = blin[j];
        for (int i = 0; i < 64; i++) out[(size_t)(t0 + i) * OUT_D + j] = acc[i] + b;
    }
}

// ---------------- helpers ----------------
__device__ __forceinline__ float fast_tanh(float v)
{
    float e = __expf(2.f * v);
    return 1.f - 2.f * __builtin_amdgcn_rcpf(e + 1.f);
}

// W row-tile fragment as f16: lane holds row = tile*16+col, k = kc*32+g*8+j; OOB zeroed.
// Identical register contents serve as A-frag (row=l&15) or B-frag (col=l&15).
__device__ __forceinline__ f16x8 loadw_frag(const float* __restrict__ W,
                                            int tile, int col, int g, int kc)
{
    const int row = tile * 16 + col;
    const int kb  = kc * 32 + g * 8;
    f16x8 f;
#pragma unroll
    for (int j = 0; j < 8; j++) {
        const int k = kb + j;
        float wv = (row < HID && k < HID) ? W[row * HID + k] : 0.f;
        f[j] = (_Float16)wv;
    }
    return f;
}

// consumer: tid0 spins with agent-scope acquire (buffer_inv), then block-wide barrier
__device__ __forceinline__ void wait_flag(int* f, int target)
{
    if (threadIdx.x == 0) {
        while (__hip_atomic_load(f, __ATOMIC_ACQUIRE, __HIP_MEMORY_SCOPE_AGENT) < target)
            __builtin_amdgcn_s_sleep(8);
    }
    __syncthreads();
}

// producer: __syncthreads drains each wave's vmcnt; release store (wbl2) publishes
__device__ __forceinline__ void publish_flag(int* f, int v)
{
    __syncthreads();
    if (threadIdx.x == 0)
        __hip_atomic_store(f, v, __ATOMIC_RELEASE, __HIP_MEMORY_SCOPE_AGENT);
}

#define MF(a_, b_, c_) __builtin_amdgcn_mfma_f32_16x16x32_f16((a_), (b_), (c_), 0, 0, 0)

// ---------------- scan role: h_t = tanh(x_t + Whh h_{t-1}) ----------------
// 12 waves (3/SIMD). 19 row-tiles of 16: wave w owns tile w; waves 0-6 also tile 12+w.
// OPERAND-SWAPPED MFMA (R13): D = h(A) x W^T(B) -> D[row][col] = y[tile*16+col]
// replicated across row-groups; extraction = acc[0]. NEW in R14: 3 chains/tile of
// depth {4,3,3} (kc {0-3},{4-6},{7-9}) — one less dependent MFMA on the critical
// path; acc = 24 regs (fits the 170-reg 3-wave/SIMD budget; 5 chains = R10's spill).
// g=0 lanes (0-15) store f16 h to LDS; g=1 lanes (16-31) store to global in parallel.
template<int ROLE0>
__device__ __forceinline__ void scan_role(_Float16 (*hlds)[HK],
                                          const float* __restrict__ Whh,
                                          const float* __restrict__ xin,
                                          _Float16* __restrict__ hseq)
{
    const int tid  = threadIdx.x;
    const int lane = tid & 63;
    const int wave = tid >> 6;       // 0..11
    const int col  = lane & 15;
    const int g    = lane >> 4;      // 0..3
    const bool wrL = (lane < 16);              // LDS h writer (g=0 replica)
    const bool wrG = (lane >= 16 && lane < 32);// global h writer (g=1 replica)

    const int tA = wave, tB = wave + NWAVE;
    const bool hasB = (wave < 7);            // tiles 12..18
    const int rowA = tA * 16 + col;          // output row this lane finalizes (<=191)
    const int rowB = tB * 16 + col;          // <=303 (< HP)

    for (int i = tid; i < 2 * HK; i += 64 * NWAVE) ((_Float16*)hlds)[i] = (_Float16)0.f;

    f16x8 wA[KC], wB[KC];
#pragma unroll
    for (int kc = 0; kc < KC; kc++) {
        wA[kc] = loadw_frag(Whh, tA, col, g, kc);
        if (hasB) wB[kc] = loadw_frag(Whh, tB, col, g, kc);
        else {
            f16x8 z;
#pragma unroll
            for (int j = 0; j < 8; j++) z[j] = (_Float16)0.f;
            wB[kc] = z;
        }
    }

    __syncthreads();

    if (!ROLE0) wait_flag(&g_flag1, NCHUNK < 2 ? NCHUNK : 2);  // chunks 0,1 of x1 ready

    // x prefetch slots: slot s holds x for the next step t with (t & 3) == s
    float xA[DIST], xB[DIST];
#pragma unroll
    for (int s = 0; s < DIST; s++) {
        xA[s] = xin[(size_t)s * HP + rowA];
        xB[s] = hasB ? xin[(size_t)s * HP + rowB] : 0.f;
    }

    const f32x4 Z = {0.f, 0.f, 0.f, 0.f};

// One timestep. bf reads first; slot consumed, refilled for t+DIST; per tile 3
// Z-seeded chains (depth 4,3,3), scalar sum ordered (a1+a2)+a0 so shallow-chain adds
// overlap the deep chain tail; tanh; g0 lanes -> LDS, g1 lanes -> global, parallel.
#define STEP(t_, R_, s_) do {                                                          \
        f16x8 bf[KC];                                                                  \
        _Pragma("unroll")                                                              \
        for (int kc = 0; kc < KC; kc++)                                                \
            bf[kc] = *(const f16x8*)&hlds[R_][kc * 32 + g * 8];                        \
        float xvA = xA[s_], xvB = xB[s_];                                              \
        xA[s_] = xin[(size_t)((t_) + DIST) * HP + rowA];                               \
        if (hasB) xB[s_] = xin[(size_t)((t_) + DIST) * HP + rowB];                     \
        f32x4 aA0 = MF(bf[0], wA[0], Z);                                               \
        f32x4 aB0 = hasB ? MF(bf[0], wB[0], Z) : Z;                                    \
        f32x4 aA1 = MF(bf[4], wA[4], Z);                                               \
        f32x4 aB1 = hasB ? MF(bf[4], wB[4], Z) : Z;                                    \
        f32x4 aA2 = MF(bf[7], wA[7], Z);                                               \
        f32x4 aB2 = hasB ? MF(bf[7], wB[7], Z) : Z;                                    \
        aA0 = MF(bf[1], wA[1], aA0);                                                   \
        if (hasB) aB0 = MF(bf[1], wB[1], aB0);                                         \
        aA1 = MF(bf[5], wA[5], aA1);                                                   \
        if (hasB) aB1 = MF(bf[5], wB[5], aB1);                                         \
        aA2 = MF(bf[8], wA[8], aA2);                                                   \
        if (hasB) aB2 = MF(bf[8], wB[8], aB2);                                         \
        aA0 = MF(bf[2], wA[2], aA0);                                                   \
        if (hasB) aB0 = MF(bf[2], wB[2], aB0);                                         \
        aA1 = MF(bf[6], wA[6], aA1);                                                   \
        if (hasB) aB1 = MF(bf[6], wB[6], aB1);                                         \
        aA2 = MF(bf[9], wA[9], aA2);                                                   \
        if (hasB) aB2 = MF(bf[9], wB[9], aB2);                                         \
        aA0 = MF(bf[3], wA[3], aA0);                                                   \
        if (hasB) aB0 = MF(bf[3], wB[3], aB0);                                         \
        float yA = fast_tanh(((aA1[0] + aA2[0]) + xvA) + aA0[0]);                      \
        float yB = 0.f;                                                                \
        if (hasB) yB = fast_tanh(((aB1[0] + aB2[0]) + xvB) + aB0[0]);                  \
        _Float16 hA = (_Float16)yA, hB = (_Float16)yB;                                 \
        if (wrL) {                                                                     \
            hlds[1 - (R_)][rowA] = hA;                                                 \
            if (hasB) hlds[1 - (R_)][rowB] = hB;                                       \
        } else if (wrG) {                                                              \
            hseq[(size_t)(t_) * HP + rowA] = hA;                                       \
            if (hasB) hseq[(size_t)(t_) * HP + rowB] = hB;                             \
        }                                                                              \
    } while (0)

// barrier with LDS drain; "memory" clobber orders memory ops but leaves ALU free to
// schedule into the barrier shadow (vmcnt never drained: x prefetch stays in flight)
#define BAR() asm volatile("s_waitcnt lgkmcnt(0)\n\ts_barrier" ::: "memory")

#pragma unroll 1
    for (int c = 0; c < NCHUNK; ++c) {
        if (!ROLE0 && c > 0) {
            int tgt = (c + 2) < NCHUNK ? (c + 2) : NCHUNK;
            wait_flag(&g_flag1, tgt);
        }
#pragma unroll 1
        for (int tt = 0; tt < CHUNK; tt += DIST) {
            const int tb = c * CHUNK + tt;
            STEP(tb + 0, 0, 0); BAR();
            STEP(tb + 1, 1, 1); BAR();
            STEP(tb + 2, 0, 2); BAR();
            STEP(tb + 3, 1, 3); BAR();
        }
        if (ROLE0) publish_flag(&g_flag0, c + 1);
    }
#undef STEP
#undef BAR
}

// ---------------- proj role: x1[t] = W_ih1 h0[t] + (b_ih1+b_hh1), chunked ----------------
__device__ __forceinline__ void proj_role(const float* __restrict__ Wih,
                                          const float* __restrict__ b1,
                                          const float* __restrict__ b2)
{
    const int tid  = threadIdx.x;
    const int lane = tid & 63;
    const int wave = tid >> 6;       // 0..11
    const int col  = lane & 15;      // timestep-within-16-group (B col / D col)
    const int g    = lane >> 4;      // k-subgroup / D row-group

    const int tA = wave, tB = wave + NWAVE;
    const bool hasB = (wave < 7);

    f16x8 wA[KC], wB[KC];
#pragma unroll
    for (int kc = 0; kc < KC; kc++) {
        wA[kc] = loadw_frag(Wih, tA, col, g, kc);
        if (hasB) wB[kc] = loadw_frag(Wih, tB, col, g, kc);
        else {
            f16x8 z;
#pragma unroll
            for (int j = 0; j < 8; j++) z[j] = (_Float16)0.f;
            wB[kc] = z;
        }
    }
    // bias vectors for this lane's 4 output rows per tile (zero for j>=HID)
    f32x4 bA, bB;
#pragma unroll
    for (int e = 0; e < 4; e++) {
        int jA = tA * 16 + g * 4 + e, jB = tB * 16 + g * 4 + e;
        bA[e] = (jA < HID) ? b1[jA] + b2[jA] : 0.f;
        bB[e] = (hasB && jB < HID) ? b1[jB] + b2[jB] : 0.f;
    }

    const f32x4 zero4 = {0.f, 0.f, 0.f, 0.f};

#pragma unroll 1
    for (int c = 0; c < NCHUNK; ++c) {
        wait_flag(&g_flag0, c + 1);
        const int tbase = c * CHUNK;
#pragma unroll
        for (int tg = 0; tg < 4; ++tg) {
            const int t = tbase + tg * 16 + col;
            f16x8 bf[KC];
#pragma unroll
            for (int kc = 0; kc < KC; ++kc)
                bf[kc] = *(const f16x8*)&g_h0h[(size_t)t * HP + kc * 32 + g * 8];
            f32x4 aA = zero4, aB = zero4;
#pragma unroll
            for (int kc = 0; kc < KC; ++kc) {
                aA = MF(wA[kc], bf[kc], aA);
                if (hasB) aB = MF(wB[kc], bf[kc], aB);
            }
            // D: col=lane&15 -> t, row=g*4+e -> j within tile; f32x4 store per tile
            *(f32x4*)&g_x1[(size_t)t * HP + tA * 16 + g * 4] = aA + bA;
            if (hasB)
            *(f32x4*)&g_x1[(size_t)t * HP + tB * 16 + g * 4] = aB + bB;
        }
        publish_flag(&g_flag1, c + 1);
    }
}

// ---------------- fused pipeline: block0=scan0, block1=proj1, block2=scan1 ----------------
__global__ __launch_bounds__(64 * NWAVE, 3) void k_pipeline(const float* __restrict__ W_hh0,
                                                            const float* __restrict__ W_ih1,
                                                            const float* __restrict__ b_ih1,
                                                            const float* __restrict__ b_hh1,
                                                            const float* __restrict__ W_hh1)
{
    __shared__ __align__(16) _Float16 hlds[2][HK];
    if (blockIdx.x == 0)
        scan_role<1>(hlds, W_hh0, g_x, g_h0h);
    else if (blockIdx.x == 1)
        proj_role(W_ih1, b_ih1, b_hh1);
    else
        scan_role<0>(hlds, W_hh1, g_x1, g_h1h);
}

extern "C" void kernel_launch(void* const* d_in, const int* in_sizes, int n_in,
                              void* d_out, int out_size, void* d_ws, size_t ws_size,
                              hipStream_t stream)
{
    (void)in_sizes; (void)n_in; (void)d_ws; (void)ws_size; (void)out_size;
    const float* input = (const float*)d_in[0];
    const float* W_ih0 = (const float*)d_in[1];
    const float* W_hh0 = (const float*)d_in[2];
    const float* b_ih0 = (const float*)d_in[3];
    const float* b_hh0 = (const float*)d_in[4];
    const float* W_ih1 = (const float*)d_in[5];
    const float* W_hh1 = (const float*)d_in[6];
    const float* b_ih1 = (const float*)d_in[7];
    const float* b_hh1 = (const float*)d_in[8];
    const float* W_lin = (const float*)d_in[9];
    const float* b_lin = (const float*)d_in[10];
    float* out = (float*)d_out;

    k_reset<<<dim3(1), dim3(1), 0, stream>>>();
    k_transpose<<<dim3((IN_D * HP + 255) / 256), dim3(256), 0, stream>>>(W_ih0, HID, IN_D, HP, 0);
    k_transpose<<<dim3((HID * OUTP + 255) / 256), dim3(256), 0, stream>>>(W_lin, OUT_D, HID, OUTP, 2);

    // x0 = input @ W_ih0^T + (b_ih0 + b_hh0)
    k_gemm_in<<<dim3(T_LEN / 32), dim3(320), 0, stream>>>(input, b_ih0, b_hh0);

    // fused scan0 | proj1 | scan1 pipeline (3 co-resident workgroups)
    k_pipeline<<<dim3(3), dim3(64 * NWAVE), 0, stream>>>(W_hh0, W_ih1, b_ih1, b_hh1, W_hh1);

    // head
    k_gemm_out<<<dim3(T_LEN / 64), dim3(128), 0, stream>>>(b_lin, out);
}

// Round 15
// 22190.689 us; speedup vs baseline: 1.1559x; 1.1559x over previous
//
#include <hip/hip_runtime.h>
#include <cstddef>

#define T_LEN 32768
#define HID   300
#define HP    304   // padded row width for x/h buffers
#define HK    320   // padded K for MFMA (10 chunks of 32)
#define KC    10
#define IN_D  500
#define OUT_D 100
#define OUTP  104
#define DIST  4     // x prefetch distance (steps) = slot count
#define CHUNK 64
#define NCHUNK (T_LEN / CHUNK)
#define NWAVE 12    // 768 threads, 3 waves/SIMD (measured optimum; 4/SIMD spills)

typedef _Float16 f16x8 __attribute__((ext_vector_type(8)));
typedef float    f32x4 __attribute__((ext_vector_type(4)));

// Static device scratch
__device__ __align__(16) float    g_x  [(size_t)(T_LEN + 8) * HP];    // x0
__device__ __align__(16) float    g_x1 [(size_t)(T_LEN + 8) * HP];    // x1
__device__ __align__(16) _Float16 g_h0h[(size_t)T_LEN * HP + 64];     // h0, f16
__device__ __align__(16) _Float16 g_h1h[(size_t)T_LEN * HP + 64];     // h1, f16
__device__ __align__(16) float    g_wt0[IN_D * HP];
__device__ __align__(16) float    g_wtl[HID * OUTP];
__device__ int g_flag0;   // chunks of h0 published by scan0
__device__ int g_flag1;   // chunks of x1 published by proj1

// ---------------- reset flags (graph replays!) ----------------
__global__ void k_reset() { g_flag0 = 0; g_flag1 = 0; }

// ---------------- transpose + pad: dst[k][j] = (j<J) ? src[j][k] : 0 ----------------
__global__ void k_transpose(const float* __restrict__ src, int J, int K, int JP, int dst_sel)
{
    float* dst = (dst_sel == 0) ? g_wt0 : g_wtl;
    int idx = blockIdx.x * 256 + threadIdx.x;
    if (idx >= K * JP) return;
    int k = idx / JP, j = idx - k * JP;
    dst[idx] = (j < J) ? src[j * K + k] : 0.f;
}

// ---------------- x0 = input @ W_ih0^T + (b_ih0+b_hh0), 32 rows per block ----------------
__global__ __launch_bounds__(320) void k_gemm_in(const float* __restrict__ inp,
                                                 const float* __restrict__ b1,
                                                 const float* __restrict__ b2)
{
    __shared__ float lds[32 * IN_D];
    const int tid = threadIdx.x;
    const int t0  = blockIdx.x * 32;
    {
        const f32x4* src4 = (const f32x4*)(inp + (size_t)t0 * IN_D);
        f32x4* lds4 = (f32x4*)lds;
        const int n4 = (32 * IN_D) >> 2;
        for (int i = tid; i < n4; i += 320) lds4[i] = src4[i];
    }
    __syncthreads();
    const int j = tid;
    if (j >= HP) return;
    float acc[32];
#pragma unroll
    for (int i = 0; i < 32; i++) acc[i] = 0.f;
#pragma unroll 4
    for (int k = 0; k < IN_D; k++) {
        float w = g_wt0[k * HP + j];
#pragma unroll
        for (int i = 0; i < 32; i++) acc[i] += w * lds[i * IN_D + k];  // uniform addr -> broadcast
    }
    const float bias = (j < HID) ? (b1[j] + b2[j]) : 0.f;
#pragma unroll 4
    for (int i = 0; i < 32; i++) g_x[(size_t)(t0 + i) * HP + j] = acc[i] + bias;
}

// ---------------- out = h1(f16) @ WTl + b_lin, 64 rows per block ----------------
__global__ __launch_bounds__(128) void k_gemm_out(const float* __restrict__ blin,
                                                  float* __restrict__ out)
{
    __shared__ float lds[64 * HP];
    const int tid = threadIdx.x;
    const int t0  = blockIdx.x * 64;
    {
        const f16x8* src8 = (const f16x8*)(g_h1h + (size_t)t0 * HP);
        const int n8 = (64 * HP) / 8;
        for (int i = tid; i < n8; i += 128) {
            f16x8 v = src8[i];
            float* d = &lds[i * 8];
#pragma unroll
            for (int e = 0; e < 8; e++) d[e] = (float)v[e];
        }
    }
    __syncthreads();
    const int j = tid;
    if (j >= OUTP) return;
    float acc[64];
#pragma unroll
    for (int i = 0; i < 64; i++) acc[i] = 0.f;
#pragma unroll 2
    for (int k = 0; k < HID; k++) {
        float w = g_wtl[k * OUTP + j];
#pragma unroll
        for (int i = 0; i < 64; i++) acc[i] += w * lds[i * HP + k];
    }
    if (j < OUT_D) {
        float b = blin[j];
        for (int i = 0; i < 64; i++) out[(size_t)(t0 + i) * OUT_D + j] = acc[i] + b;
    }
}

// ---------------- helpers ----------------
__device__ __forceinline__ float fast_tanh(float v)
{
    float e = __expf(2.f * v);
    return 1.f - 2.f * __builtin_amdgcn_rcpf(e + 1.f);
}

// W row-tile fragment as f16: lane holds row = tile*16+col, k = kc*32+g*8+j; OOB zeroed.
// Identical register contents serve as A-frag (row=l&15) or B-frag (col=l&15).
__device__ __forceinline__ f16x8 loadw_frag(const float* __restrict__ W,
                                            int tile, int col, int g, int kc)
{
    const int row = tile * 16 + col;
    const int kb  = kc * 32 + g * 8;
    f16x8 f;
#pragma unroll
    for (int j = 0; j < 8; j++) {
        const int k = kb + j;
        float wv = (row < HID && k < HID) ? W[row * HID + k] : 0.f;
        f[j] = (_Float16)wv;
    }
    return f;
}

// consumer: tid0 spins with agent-scope acquire (buffer_inv), then block-wide barrier
__device__ __forceinline__ void wait_flag(int* f, int target)
{
    if (threadIdx.x == 0) {
        while (__hip_atomic_load(f, __ATOMIC_ACQUIRE, __HIP_MEMORY_SCOPE_AGENT) < target)
            __builtin_amdgcn_s_sleep(8);
    }
    __syncthreads();
}

// producer: __syncthreads drains each wave's vmcnt; release store (wbl2) publishes
__device__ __forceinline__ void publish_flag(int* f, int v)
{
    __syncthreads();
    if (threadIdx.x == 0)
        __hip_atomic_store(f, v, __ATOMIC_RELEASE, __HIP_MEMORY_SCOPE_AGENT);
}

#define MF(a_, b_, c_) __builtin_amdgcn_mfma_f32_16x16x32_f16((a_), (b_), (c_), 0, 0, 0)

// ---------------- scan role: h_t = tanh(x_t + Whh h_{t-1}) ----------------
// 12 waves (3/SIMD). 19 row-tiles of 16: wave w owns tile w; waves 0-6 also tile 12+w.
// OPERAND-SWAPPED MFMA (R13 optimum): D = h(A) x W^T(B) -> D[row][col] =
// y[tile*16+col] replicated across row-groups. Extraction = acc[0] (scalar);
// no sel4/cndmask; writers = lanes 0-15. 2 chains of depth 5 per tile (measured
// optimum; 3-chain and K-split both regressed). Scalar x slots (DIST=4), one
// lgkmcnt+s_barrier per step, vmcnt never drained in-loop.
template<int ROLE0>
__device__ __forceinline__ void scan_role(_Float16 (*hlds)[HK],
                                          const float* __restrict__ Whh,
                                          const float* __restrict__ xin,
                                          _Float16* __restrict__ hseq)
{
    const int tid  = threadIdx.x;
    const int lane = tid & 63;
    const int wave = tid >> 6;       // 0..11
    const int col  = lane & 15;
    const int g    = lane >> 4;      // 0..3
    const bool writer = (lane < 16); // replica row-group 0 holds all outputs

    const int tA = wave, tB = wave + NWAVE;
    const bool hasB = (wave < 7);            // tiles 12..18
    const int rowA = tA * 16 + col;          // output row this lane finalizes (<=191)
    const int rowB = tB * 16 + col;          // <=303 (< HP)

    for (int i = tid; i < 2 * HK; i += 64 * NWAVE) ((_Float16*)hlds)[i] = (_Float16)0.f;

    f16x8 wA[KC], wB[KC];
#pragma unroll
    for (int kc = 0; kc < KC; kc++) {
        wA[kc] = loadw_frag(Whh, tA, col, g, kc);
        if (hasB) wB[kc] = loadw_frag(Whh, tB, col, g, kc);
        else {
            f16x8 z;
#pragma unroll
            for (int j = 0; j < 8; j++) z[j] = (_Float16)0.f;
            wB[kc] = z;
        }
    }

    __syncthreads();

    if (!ROLE0) wait_flag(&g_flag1, NCHUNK < 2 ? NCHUNK : 2);  // chunks 0,1 of x1 ready

    // x prefetch slots: slot s holds x for the next step t with (t & 3) == s
    float xA[DIST], xB[DIST];
#pragma unroll
    for (int s = 0; s < DIST; s++) {
        xA[s] = xin[(size_t)s * HP + rowA];
        xB[s] = hasB ? xin[(size_t)s * HP + rowB] : 0.f;
    }

    const f32x4 Z = {0.f, 0.f, 0.f, 0.f};

// One timestep (R13 structure). bf reads first; slot consumed, refilled for t+DIST;
// per tile 2 chains of 5 seeded via mfma(bf,w,Z); scalar extraction acc[0]+acc[0];
// tanh; writer lanes publish f16 h to hlds[1-R] + global.
#define STEP(t_, R_, s_) do {                                                          \
        f16x8 bf[KC];                                                                  \
        _Pragma("unroll")                                                              \
        for (int kc = 0; kc < KC; kc++)                                                \
            bf[kc] = *(const f16x8*)&hlds[R_][kc * 32 + g * 8];                        \
        float xvA = xA[s_], xvB = xB[s_];                                              \
        xA[s_] = xin[(size_t)((t_) + DIST) * HP + rowA];                               \
        if (hasB) xB[s_] = xin[(size_t)((t_) + DIST) * HP + rowB];                     \
        f32x4 aA0 = MF(bf[0], wA[0], Z);                                               \
        f32x4 aB0 = hasB ? MF(bf[0], wB[0], Z) : Z;                                    \
        f32x4 aA1 = MF(bf[5], wA[5], Z);                                               \
        f32x4 aB1 = hasB ? MF(bf[5], wB[5], Z) : Z;                                    \
        _Pragma("unroll")                                                              \
        for (int j = 1; j < 5; j++) {                                                  \
            aA0 = MF(bf[j], wA[j], aA0);                                               \
            if (hasB) aB0 = MF(bf[j], wB[j], aB0);                                     \
            aA1 = MF(bf[j + 5], wA[j + 5], aA1);                                       \
            if (hasB) aB1 = MF(bf[j + 5], wB[j + 5], aB1);                             \
        }                                                                              \
        float yA = fast_tanh(aA0[0] + aA1[0] + xvA);                                   \
        float yB = 0.f;                                                                \
        if (hasB) yB = fast_tanh(aB0[0] + aB1[0] + xvB);                               \
        if (writer) {                                                                  \
            _Float16 hA = (_Float16)yA, hB = (_Float16)yB;                             \
            hlds[1 - (R_)][rowA] = hA;                                                 \
            if (hasB) hlds[1 - (R_)][rowB] = hB;                                       \
            hseq[(size_t)(t_) * HP + rowA] = hA;                                       \
            if (hasB) hseq[(size_t)(t_) * HP + rowB] = hB;                             \
        }                                                                              \
    } while (0)

// barrier with LDS drain; "memory" clobber orders memory ops but leaves ALU free to
// schedule into the barrier shadow (vmcnt never drained: x prefetch stays in flight)
#define BAR() asm volatile("s_waitcnt lgkmcnt(0)\n\ts_barrier" ::: "memory")

#pragma unroll 1
    for (int c = 0; c < NCHUNK; ++c) {
        if (!ROLE0 && c > 0) {
            int tgt = (c + 2) < NCHUNK ? (c + 2) : NCHUNK;
            wait_flag(&g_flag1, tgt);
        }
#pragma unroll 1
        for (int tt = 0; tt < CHUNK; tt += DIST) {
            const int tb = c * CHUNK + tt;
            STEP(tb + 0, 0, 0); BAR();
            STEP(tb + 1, 1, 1); BAR();
            STEP(tb + 2, 0, 2); BAR();
            STEP(tb + 3, 1, 3); BAR();
        }
        if (ROLE0) publish_flag(&g_flag0, c + 1);
    }
#undef STEP
#undef BAR
}

// ---------------- proj role: x1[t] = W_ih1 h0[t] + (b_ih1+b_hh1), chunked ----------------
__device__ __forceinline__ void proj_role(const float* __restrict__ Wih,
                                          const float* __restrict__ b1,
                                          const float* __restrict__ b2)
{
    const int tid  = threadIdx.x;
    const int lane = tid & 63;
    const int wave = tid >> 6;       // 0..11
    const int col  = lane & 15;      // timestep-within-16-group (B col / D col)
    const int g    = lane >> 4;      // k-subgroup / D row-group

    const int tA = wave, tB = wave + NWAVE;
    const bool hasB = (wave < 7);

    f16x8 wA[KC], wB[KC];
#pragma unroll
    for (int kc = 0; kc < KC; kc++) {
        wA[kc] = loadw_frag(Wih, tA, col, g, kc);
        if (hasB) wB[kc] = loadw_frag(Wih, tB, col, g, kc);
        else {
            f16x8 z;
#pragma unroll
            for (int j = 0; j < 8; j++) z[j] = (_Float16)0.f;
            wB[kc] = z;
        }
    }
    // bias vectors for this lane's 4 output rows per tile (zero for j>=HID)
    f32x4 bA, bB;
#pragma unroll
    for (int e = 0; e < 4; e++) {
        int jA = tA * 16 + g * 4 + e, jB = tB * 16 + g * 4 + e;
        bA[e] = (jA < HID) ? b1[jA] + b2[jA] : 0.f;
        bB[e] = (hasB && jB < HID) ? b1[jB] + b2[jB] : 0.f;
    }

    const f32x4 zero4 = {0.f, 0.f, 0.f, 0.f};

#pragma unroll 1
    for (int c = 0; c < NCHUNK; ++c) {
        wait_flag(&g_flag0, c + 1);
        const int tbase = c * CHUNK;
#pragma unroll
        for (int tg = 0; tg < 4; ++tg) {
            const int t = tbase + tg * 16 + col;
            f16x8 bf[KC];
#pragma unroll
            for (int kc = 0; kc < KC; ++kc)
                bf[kc] = *(const f16x8*)&g_h0h[(size_t)t * HP + kc * 32 + g * 8];
            f32x4 aA = zero4, aB = zero4;
#pragma unroll
            for (int kc = 0; kc < KC; ++kc) {
                aA = MF(wA[kc], bf[kc], aA);
                if (hasB) aB = MF(wB[kc], bf[kc], aB);
            }
            // D: col=lane&15 -> t, row=g*4+e -> j within tile; f32x4 store per tile
            *(f32x4*)&g_x1[(size_t)t * HP + tA * 16 + g * 4] = aA + bA;
            if (hasB)
            *(f32x4*)&g_x1[(size_t)t * HP + tB * 16 + g * 4] = aB + bB;
        }
        publish_flag(&g_flag1, c + 1);
    }
}

// ---------------- fused pipeline: block0=scan0, block1=proj1, block2=scan1 ----------------
__global__ __launch_bounds__(64 * NWAVE, 3) void k_pipeline(const float* __restrict__ W_hh0,
                                                            const float* __restrict__ W_ih1,
                                                            const float* __restrict__ b_ih1,
                                                            const float* __restrict__ b_hh1,
                                                            const float* __restrict__ W_hh1)
{
    __shared__ __align__(16) _Float16 hlds[2][HK];
    if (blockIdx.x == 0)
        scan_role<1>(hlds, W_hh0, g_x, g_h0h);
    else if (blockIdx.x == 1)
        proj_role(W_ih1, b_ih1, b_hh1);
    else
        scan_role<0>(hlds, W_hh1, g_x1, g_h1h);
}

extern "C" void kernel_launch(void* const* d_in, const int* in_sizes, int n_in,
                              void* d_out, int out_size, void* d_ws, size_t ws_size,
                              hipStream_t stream)
{
    (void)in_sizes; (void)n_in; (void)d_ws; (void)ws_size; (void)out_size;
    const float* input = (const float*)d_in[0];
    const float* W_ih0 = (const float*)d_in[1];
    const float* W_hh0 = (const float*)d_in[2];
    const float* b_ih0 = (const float*)d_in[3];
    const float* b_hh0 = (const float*)d_in[4];
    const float* W_ih1 = (const float*)d_in[5];
    const float* W_hh1 = (const float*)d_in[6];
    const float* b_ih1 = (const float*)d_in[7];
    const float* b_hh1 = (const float*)d_in[8];
    const float* W_lin = (const float*)d_in[9];
    const float* b_lin = (const float*)d_in[10];
    float* out = (float*)d_out;

    k_reset<<<dim3(1), dim3(1), 0, stream>>>();
    k_transpose<<<dim3((IN_D * HP + 255) / 256), dim3(256), 0, stream>>>(W_ih0, HID, IN_D, HP, 0);
    k_transpose<<<dim3((HID * OUTP + 255) / 256), dim3(256), 0, stream>>>(W_lin, OUT_D, HID, OUTP, 2);

    // x0 = input @ W_ih0^T + (b_ih0 + b_hh0)
    k_gemm_in<<<dim3(T_LEN / 32), dim3(320), 0, stream>>>(input, b_ih0, b_hh0);

    // fused scan0 | proj1 | scan1 pipeline (3 co-resident workgroups)
    k_pipeline<<<dim3(3), dim3(64 * NWAVE), 0, stream>>>(W_hh0, W_ih1, b_ih1, b_hh1, W_hh1);

    // head
    k_gemm_out<<<dim3(T_LEN / 64), dim3(128), 0, stream>>>(b_lin, out);
}